// Round 1
// baseline (461.934 us; speedup 1.0000x reference)
//
#include <hip/hip_runtime.h>

// QRNN fo-pool: T=65536, E=512, H=512 (kernel_size=2)
// gates[T,1536] = concat(x, shift(x)) @ W + b ; z=tanh, f,o=sigmoid
// c_t = f_t c_{t-1} + (1-f_t) z_t ; h_t = o_t c_t
// out = [hiddens (T*512) | h_last (512) | c_last (512)]  (f32)

#define T_LEN 65536
#define E_DIM 512
#define H3    1536
#define K_DIM 1024
#define LC    256
#define NCHUNK (T_LEN / LC)   // 256

typedef float f32x4 __attribute__((ext_vector_type(4)));
typedef short bf16x8 __attribute__((ext_vector_type(8)));

__device__ __forceinline__ unsigned short f2bf(float f) {
    unsigned int x = __builtin_bit_cast(unsigned int, f);
    x += 0x7fffu + ((x >> 16) & 1u);          // round-to-nearest-even
    return (unsigned short)(x >> 16);
}
__device__ __forceinline__ float bf2f(unsigned short u) {
    return __builtin_bit_cast(float, ((unsigned int)u) << 16);
}
__device__ __forceinline__ float fsig(float x)  { return 1.f / (1.f + __expf(-x)); }
__device__ __forceinline__ float ftanh(float x) { return 2.f / (1.f + __expf(-2.f * x)) - 1.f; }

__device__ __forceinline__ void gload_lds16(const void* g, void* l) {
    __builtin_amdgcn_global_load_lds((const __attribute__((address_space(1))) void*)g,
                                     (__attribute__((address_space(3))) void*)l, 16, 0, 0);
}

// ---- prep: x (f32) -> bf16 with 512-element zero prefix ------------------
__global__ void prep_x(const float* __restrict__ x, unsigned short* __restrict__ xp) {
    const long long nq = (512LL + (long long)T_LEN * E_DIM) / 4;
    for (long long q = (long long)blockIdx.x * blockDim.x + threadIdx.x; q < nq;
         q += (long long)gridDim.x * blockDim.x) {
        ushort4 u;
        if (q < 128) {
            u.x = 0; u.y = 0; u.z = 0; u.w = 0;
        } else {
            const float4 v = *reinterpret_cast<const float4*>(x + q * 4 - 512);
            u.x = f2bf(v.x); u.y = f2bf(v.y); u.z = f2bf(v.z); u.w = f2bf(v.w);
        }
        *reinterpret_cast<ushort4*>(xp + q * 4) = u;
    }
}

// ---- prep: W [1024,1536] f32 -> Wt [1536,1024] bf16 ----------------------
__global__ void prep_w(const float* __restrict__ W, unsigned short* __restrict__ Wt) {
    const int n_el = K_DIM * H3;
    for (int i = blockIdx.x * blockDim.x + threadIdx.x; i < n_el;
         i += gridDim.x * blockDim.x) {
        const int k = i / H3, n = i - k * H3;
        Wt[n * K_DIM + k] = f2bf(W[i]);
    }
}

// ---- GEMM: gates = A @ W + b, activation, store z,f,o bf16 ---------------
// A[t][k] = xp[512 + t*512 + k - (k>=512 ? 1024 : 0)]   (xp has zero prefix)
// 128x128 tile, BK=32, 4 waves of 64x64, mfma 16x16x32 bf16
__global__ __launch_bounds__(256) void gemm_gates(
    const unsigned short* __restrict__ xp,
    const unsigned short* __restrict__ Wt,
    const float* __restrict__ bias,
    unsigned short* __restrict__ zfo)
{
    __shared__ unsigned short Alds[128 * 32];
    __shared__ unsigned short Blds[128 * 32];

    const int tid  = threadIdx.x;
    const int lane = tid & 63;
    const int w    = tid >> 6;           // wave 0..3
    const int wr   = w >> 1, wc = w & 1; // 2x2 wave grid, 64x64 each

    const int  nt = blockIdx.x;          // 0..11
    const int  mt = blockIdx.y;          // 0..511
    const long long t0 = (long long)mt * 128;
    const int  nb = nt * 128;

    f32x4 acc[4][4] = {};

    const int r_in = lane >> 2;          // 0..15 (staging row within 16-row group)
    const int c8   = (lane & 3) * 8;     // staging k-offset (elements)
    const int ko   = (lane >> 4) * 8;    // fragment k-offset
    const int l15  = lane & 15;

    for (int kt = 0; kt < 32; ++kt) {
        const int kb = kt * 32;
        const long long abase = (kb >= 512) ? (long long)(kb - 512) : (long long)(512 + kb);
        __syncthreads();                 // prev tile fully consumed
        #pragma unroll
        for (int j = 0; j < 2; ++j) {
            const int row = j * 64 + w * 16 + r_in;      // 0..127
            const unsigned short* ga = xp + abase + (t0 + row) * 512 + c8;
            gload_lds16(ga, &Alds[(j * 64 + w * 16) * 32]);
            const unsigned short* gb = Wt + (long long)(nb + row) * 1024 + kb + c8;
            gload_lds16(gb, &Blds[(j * 64 + w * 16) * 32]);
        }
        __syncthreads();                 // drains vmcnt: tiles ready
        bf16x8 af[4], bfr[4];
        #pragma unroll
        for (int m = 0; m < 4; ++m)
            af[m] = *reinterpret_cast<const bf16x8*>(&Alds[(wr * 64 + m * 16 + l15) * 32 + ko]);
        #pragma unroll
        for (int n = 0; n < 4; ++n)
            bfr[n] = *reinterpret_cast<const bf16x8*>(&Blds[(wc * 64 + n * 16 + l15) * 32 + ko]);
        #pragma unroll
        for (int m = 0; m < 4; ++m)
            #pragma unroll
            for (int n = 0; n < 4; ++n)
                acc[m][n] = __builtin_amdgcn_mfma_f32_16x16x32_bf16(af[m], bfr[n], acc[m][n], 0, 0, 0);
    }

    // epilogue: bias + activation (uniform per n-tile: 512 % 128 == 0), bf16 store
    const int cls = nb >> 9;             // 0=z(tanh), 1=f, 2=o (sigmoid)
    float bn[4];
    #pragma unroll
    for (int n = 0; n < 4; ++n) bn[n] = bias[nb + wc * 64 + n * 16 + l15];
    #pragma unroll
    for (int m = 0; m < 4; ++m) {
        #pragma unroll
        for (int n = 0; n < 4; ++n) {
            const int col = nb + wc * 64 + n * 16 + l15;
            #pragma unroll
            for (int j = 0; j < 4; ++j) {
                const long long row = t0 + wr * 64 + m * 16 + (lane >> 4) * 4 + j;
                float v = acc[m][n][j] + bn[n];
                v = (cls == 0) ? ftanh(v) : fsig(v);
                zfo[row * H3 + col] = f2bf(v);
            }
        }
    }
}

// ---- scan pass 1: per-chunk local scan (c_init = 0) + product of f -------
__global__ void scan_pass1(const unsigned short* __restrict__ zfo,
                           float* __restrict__ P, float* __restrict__ L) {
    const int chunk = blockIdx.x >> 1;
    const int ch    = (blockIdx.x & 1) * 256 + threadIdx.x;
    const long long tbase = (long long)chunk * LC;
    float c = 0.f, p = 1.f;
    #pragma unroll 4
    for (int t = 0; t < LC; ++t) {
        const long long off = (tbase + t) * H3;
        const float z = bf2f(zfo[off + ch]);
        const float f = bf2f(zfo[off + 512 + ch]);
        c = f * c + (1.f - f) * z;
        p *= f;
    }
    P[chunk * 512 + ch] = p;
    L[chunk * 512 + ch] = c;
}

// ---- scan pass 2: sequential combine over chunks (tiny) ------------------
__global__ void scan_pass2(const float* __restrict__ P, const float* __restrict__ L,
                           float* __restrict__ carry, float* __restrict__ out) {
    const int ch = threadIdx.x; // 512
    float c = 0.f;
    for (int k = 0; k < NCHUNK; ++k) {
        carry[k * 512 + ch] = c;
        c = P[k * 512 + ch] * c + L[k * 512 + ch];
    }
    out[(long long)T_LEN * 512 + 512 + ch] = c;   // cells[-1]
}

// ---- scan pass 3: replay with carry-in, write h = o*c --------------------
__global__ void scan_pass3(const unsigned short* __restrict__ zfo,
                           const float* __restrict__ carry,
                           float* __restrict__ out) {
    const int chunk = blockIdx.x >> 1;
    const int ch    = (blockIdx.x & 1) * 256 + threadIdx.x;
    float c = carry[chunk * 512 + ch];
    const long long tbase = (long long)chunk * LC;
    float h = 0.f;
    #pragma unroll 4
    for (int t = 0; t < LC; ++t) {
        const long long off = (tbase + t) * H3;
        const float z = bf2f(zfo[off + ch]);
        const float f = bf2f(zfo[off + 512 + ch]);
        const float o = bf2f(zfo[off + 1024 + ch]);
        c = f * c + (1.f - f) * z;
        h = o * c;
        out[(tbase + t) * 512 + ch] = h;
    }
    if (chunk == NCHUNK - 1) out[(long long)T_LEN * 512 + ch] = h;  // hiddens[-1]
}

extern "C" void kernel_launch(void* const* d_in, const int* in_sizes, int n_in,
                              void* d_out, int out_size, void* d_ws, size_t ws_size,
                              hipStream_t stream) {
    const float* x = (const float*)d_in[0];   // [65536, 512]
    const float* W = (const float*)d_in[1];   // [1024, 1536]
    const float* b = (const float*)d_in[2];   // [1536]
    float* out = (float*)d_out;

    // ws layout (bytes): needs ~261 MiB total
    char* ws = (char*)d_ws;
    unsigned short* xp  = (unsigned short*)(ws);                         // (512 + T*512)*2 = 67,109,888
    unsigned short* Wt  = (unsigned short*)(ws + 67110912LL);            // 1536*1024*2    =  3,145,728
    unsigned short* zfo = (unsigned short*)(ws + 70256640LL);            // T*1536*2       = 201,326,592
    float* P     = (float*)(ws + 271583232LL);                           // 256*512*4
    float* L     = (float*)(ws + 272107520LL);
    float* carry = (float*)(ws + 272631808LL);                           // ends ~273.2 MB

    prep_x<<<4096, 256, 0, stream>>>(x, xp);
    prep_w<<<768, 256, 0, stream>>>(W, Wt);

    dim3 gg(H3 / 128, T_LEN / 128, 1);     // 12 x 512
    gemm_gates<<<gg, 256, 0, stream>>>(xp, Wt, b, zfo);

    scan_pass1<<<NCHUNK * 2, 256, 0, stream>>>(zfo, P, L);
    scan_pass2<<<1, 512, 0, stream>>>(P, L, carry, out);
    scan_pass3<<<NCHUNK * 2, 256, 0, stream>>>(zfo, carry, out);
}